// Round 3
// baseline (3849.024 us; speedup 1.0000x reference)
//
#include <hip/hip_runtime.h>
#include <cstdint>

#define B_    512
#define T_    64
#define VOCAB_ 10000
#define EMB_  512
#define HID_  1024
#define G4H_  4096      // 4*HID
#define KCAT_ 1536      // EMB + HID
#define NIMG_ 2048
#define NBLK_ 512       // persistent grid: (8 bx, 64 by)

typedef _Float16 half8 __attribute__((ext_vector_type(8)));
typedef float floatx4 __attribute__((ext_vector_type(4)));

// Async global->LDS, 16B per lane. LDS dest = wave-uniform base (HW adds
// lane*16). Per-lane SOURCE address is free (gather OK).
__device__ __forceinline__ void async_copy16(void* lds_uniform, const void* gsrc) {
    __builtin_amdgcn_global_load_lds(
        (__attribute__((address_space(1))) void*)(uintptr_t)gsrc,
        (__attribute__((address_space(3))) void*)(uint32_t)(uintptr_t)lds_uniform,
        16, 0, 0);
}

__device__ __forceinline__ float fsig(float x)  { return 1.0f / (1.0f + __expf(-x)); }
__device__ __forceinline__ float ftanh(float x) { return 1.0f - 2.0f / (__expf(2.0f * x) + 1.0f); }

// Gate-interleaved weight-row permutation:
//   n_perm = jblk*64 + gate*16 + jlo   <->   n_orig = gate*HID + (jblk*16 + jlo)
// Block (bx,by): rows b0..b0+63, perm-cols n0..n0+63; wave wid = gate,
// covering cols n0 + wid*16 + lcol  (j = by*16 + lcol).

// ---------------------------------------------------------------------------
// One-time: emb->f16, Wc16 = permuted [W_ih|W_hh] (4096 x 1536), Wout16,
// biasp = permuted (b_ih+b_hh), hA = 0, tokperm[t*B+b] = m[b][t], barrier cnt = 0.
// ---------------------------------------------------------------------------
__global__ __launch_bounds__(256) void convert_kernel(
    const int* __restrict__ m, const float* __restrict__ emb,
    const float* __restrict__ W_ih, const float* __restrict__ W_hh,
    const float* __restrict__ b_ih, const float* __restrict__ b_hh,
    const float* __restrict__ W_out,
    _Float16* __restrict__ emb16, _Float16* __restrict__ Wc16,
    _Float16* __restrict__ Wout16, float* __restrict__ biasp,
    _Float16* __restrict__ hA, int* __restrict__ tokperm,
    unsigned* __restrict__ cnt)
{
    const long long EMB_N = (long long)VOCAB_ * EMB_;
    const long long WC_N  = (long long)G4H_ * KCAT_;
    const long long WO_N  = (long long)NIMG_ * HID_;
    const long long BI_N  = G4H_;
    const long long ST_N  = (long long)B_ * HID_;
    const long long TK_N  = (long long)B_ * T_;

    long long i = (long long)blockIdx.x * 256 + threadIdx.x;
    if (i < EMB_N) { emb16[i] = (_Float16)emb[i]; return; }
    i -= EMB_N;
    if (i < WC_N) {
        int n_perm = (int)(i / KCAT_);
        int k      = (int)(i % KCAT_);
        int gate = (n_perm >> 4) & 3;
        int j    = (n_perm >> 6) * 16 + (n_perm & 15);
        int n_orig = gate * HID_ + j;
        float v = (k < EMB_) ? W_ih[(size_t)n_orig * EMB_ + k]
                             : W_hh[(size_t)n_orig * HID_ + (k - EMB_)];
        Wc16[i] = (_Float16)v;
        return;
    }
    i -= WC_N;
    if (i < WO_N) { Wout16[i] = (_Float16)W_out[i]; return; }
    i -= WO_N;
    if (i < BI_N) {
        int n_perm = (int)i;
        int gate = (n_perm >> 4) & 3;
        int j    = (n_perm >> 6) * 16 + (n_perm & 15);
        biasp[i] = b_ih[gate * HID_ + j] + b_hh[gate * HID_ + j];
        return;
    }
    i -= BI_N;
    if (i < ST_N) { hA[i] = (_Float16)0.0f; return; }
    i -= ST_N;
    if (i < TK_N) {
        int t = (int)(i / B_), b = (int)(i % B_);
        tokperm[i] = m[(size_t)b * T_ + t];
        return;
    }
    i -= TK_N;
    if (i == 0) *cnt = 0u;
}

// ---------------------------------------------------------------------------
// Persistent recurrent kernel: all 64 LSTM steps in one launch.
// 512 blocks x 256 thr, 2 blocks/CU (launch_bounds(256,2): VGPR<=256,
// LDS 64.5KB <= 80KB). Weights (64 cols x K=1536) live in VGPRs (192/lane).
// c-state lives in 4 VGPRs/thread. Steps separated by device-scope barrier.
// ---------------------------------------------------------------------------
__global__ __launch_bounds__(256, 2) void lstm_persistent(
    const _Float16* __restrict__ emb16, const int* __restrict__ tokperm,
    const _Float16* __restrict__ Wc16, const float* __restrict__ biasp,
    _Float16* __restrict__ hA, _Float16* __restrict__ hB,
    unsigned* __restrict__ cnt)
{
    // LDS: As double slab 2x32KB (aliased by 17.4KB gate buffer in epilogue)
    __shared__ __align__(16) char smem[65536];
    __shared__ int tok_s[64];

    const int tid  = threadIdx.x;
    const int wid  = tid >> 6;    // wave = gate
    const int lane = tid & 63;
    const int lcol = lane & 15;
    const int quad = lane >> 4;
    const int b0   = blockIdx.x * 64;
    const int by   = blockIdx.y;
    const int n0   = by * 64;

    // ---- preload weights into registers: 48 k-iters x 8 halves = 192 VGPR ----
    const int nrow = n0 + wid * 16 + lcol;
    const _Float16* wptr = Wc16 + (size_t)nrow * KCAT_ + quad * 8;
    half8 bf[48];
#pragma unroll
    for (int ki = 0; ki < 48; ++ki)
        bf[ki] = *(const half8*)&wptr[ki * 32];
    const float bcol = biasp[nrow];

    // ---- persistent cell state (this thread owns rows rg*4..+3, col j) ----
    const int jlo = tid & 15;     // epilogue col within tile
    const int rg  = tid >> 4;     // epilogue row group (0..15)
    float cst[4] = {0.f, 0.f, 0.f, 0.f};

    const int ar = tid >> 2;      // staging row 0..63
    const int kq = tid & 3;       // 16B chunk in k32 group

    for (int t = 0; t < T_; ++t) {
        const _Float16* h_prev = (t & 1) ? hB : hA;
        _Float16*       h_next = (t & 1) ? hA : hB;

        if (tid < 64) tok_s[tid] = tokperm[t * B_ + b0 + tid];
        __syncthreads();
        const _Float16* esrc = emb16 + (size_t)tok_s[ar] * EMB_ + kq * 8;
        const _Float16* hsrc = h_prev + (size_t)(b0 + ar) * HID_ + kq * 8;

        floatx4 acc[4];
#pragma unroll
        for (int mi = 0; mi < 4; ++mi) acc[mi] = (floatx4){bcol, bcol, bcol, bcol};

        // issue slab s: 8 k32-iters, 32KB, into smem[(s&1)*32768]
        auto issue_slab = [&](int s) {
            char* dst = smem + ((s & 1) << 15) + (wid << 10);
            if (s < 2) {
#pragma unroll
                for (int i = 0; i < 8; ++i)
                    async_copy16(dst + i * 4096, esrc + s * 256 + i * 32);
            } else {
#pragma unroll
                for (int i = 0; i < 8; ++i)
                    async_copy16(dst + i * 4096, hsrc + (s - 2) * 256 + i * 32);
            }
        };

        issue_slab(0);
        __syncthreads();                       // drain slab 0
#pragma unroll
        for (int s = 0; s < 6; ++s) {
            if (s + 1 < 6) issue_slab(s + 1);  // overlaps compute below
            const _Float16* Ah = (const _Float16*)(smem + ((s & 1) << 15));
            half8 af[4];
#pragma unroll
            for (int i = 0; i < 8; ++i) {
#pragma unroll
                for (int mi = 0; mi < 4; ++mi)
                    af[mi] = *(const half8*)&Ah[(i * 64 + mi * 16 + lcol) * 32 + quad * 8];
#pragma unroll
                for (int mi = 0; mi < 4; ++mi)
                    acc[mi] = __builtin_amdgcn_mfma_f32_16x16x32_f16(
                        af[mi], bf[s * 8 + i], acc[mi], 0, 0, 0);
            }
            __syncthreads();                   // drain slab s+1; free As[s&1]
        }

        // ---- cross-wave gate exchange (gbuf aliases As[0], stride 17 pads banks)
        float* gb = (float*)smem;
#pragma unroll
        for (int mi = 0; mi < 4; ++mi)
#pragma unroll
            for (int r = 0; r < 4; ++r)
                gb[(wid * 64 + mi * 16 + quad * 4 + r) * 17 + lcol] = acc[mi][r];
        __syncthreads();

        // ---- fused LSTM cell: c in VGPRs, write h_next (f16) ----
#pragma unroll
        for (int r = 0; r < 4; ++r) {
            const int row = rg * 4 + r;
            const float iv = fsig(gb[(0 * 64 + row) * 17 + jlo]);
            const float fv = fsig(gb[(1 * 64 + row) * 17 + jlo]);
            const float gv = ftanh(gb[(2 * 64 + row) * 17 + jlo]);
            const float ov = fsig(gb[(3 * 64 + row) * 17 + jlo]);
            cst[r] = fv * cst[r] + iv * gv;
            h_next[(size_t)(b0 + row) * HID_ + by * 16 + jlo] =
                (_Float16)(ov * ftanh(cst[r]));
        }

        // ---- device-scope barrier (monotonic counter; poison-safe) ----
        __syncthreads();                       // drains vmcnt: h stores in L2
        if (tid == 0) {
            __threadfence();                   // L2 writeback to coherence point
            __hip_atomic_fetch_add(cnt, 1u, __ATOMIC_RELEASE, __HIP_MEMORY_SCOPE_AGENT);
            const unsigned target = (unsigned)(t + 1) * NBLK_;
            while (__hip_atomic_load(cnt, __ATOMIC_ACQUIRE, __HIP_MEMORY_SCOPE_AGENT) < target)
                __builtin_amdgcn_s_sleep(8);
        }
        __syncthreads();
    }
}

// ---------------------------------------------------------------------------
// Final projection GEMM (unpermuted): Out = h @ Wout16^T + b_out
// ---------------------------------------------------------------------------
__global__ __launch_bounds__(256) void gemm_out(
    const _Float16* __restrict__ A, const _Float16* __restrict__ Bw,
    const float* __restrict__ bias, float* __restrict__ Out, int N, int K)
{
    __shared__ __align__(16) _Float16 As[64 * 32];
    __shared__ __align__(16) _Float16 Bs[128 * 32];

    const int tid  = threadIdx.x;
    const int wid  = tid >> 6;
    const int lane = tid & 63;
    const int lcol = lane & 15;
    const int quad = lane >> 4;
    const int wm   = wid >> 1;
    const int wn   = wid & 1;

    const int b0 = blockIdx.x * 64;
    const int n0 = blockIdx.y * 128;

    floatx4 acc[2][4];
#pragma unroll
    for (int i = 0; i < 2; ++i)
#pragma unroll
        for (int j = 0; j < 4; ++j) acc[i][j] = (floatx4){0.f, 0.f, 0.f, 0.f};

    const int ar = tid >> 2;
    const int kq = tid & 3;

    for (int k0 = 0; k0 < K; k0 += 32) {
        async_copy16((char*)As + (wid << 10), A + (size_t)(b0 + ar) * K + (k0 + kq * 8));
        async_copy16((char*)Bs + (wid << 10), Bw + (size_t)(n0 + ar) * K + (k0 + kq * 8));
        async_copy16((char*)Bs + 4096 + (wid << 10),
                     Bw + (size_t)(n0 + 64 + ar) * K + (k0 + kq * 8));
        __syncthreads();

        half8 af[2], bfr[4];
#pragma unroll
        for (int mi = 0; mi < 2; ++mi)
            af[mi] = *(const half8*)&As[(wm * 32 + mi * 16 + lcol) * 32 + quad * 8];
#pragma unroll
        for (int ni = 0; ni < 4; ++ni)
            bfr[ni] = *(const half8*)&Bs[(wn * 64 + ni * 16 + lcol) * 32 + quad * 8];
#pragma unroll
        for (int mi = 0; mi < 2; ++mi)
#pragma unroll
            for (int ni = 0; ni < 4; ++ni)
                acc[mi][ni] = __builtin_amdgcn_mfma_f32_16x16x32_f16(
                    af[mi], bfr[ni], acc[mi][ni], 0, 0, 0);
        __syncthreads();
    }

#pragma unroll
    for (int mi = 0; mi < 2; ++mi) {
#pragma unroll
        for (int ni = 0; ni < 4; ++ni) {
            const int row = b0 + wm * 32 + mi * 16 + quad * 4;
            const int col = n0 + wn * 64 + ni * 16 + lcol;
            const float bv = bias[col];
#pragma unroll
            for (int r = 0; r < 4; ++r)
                Out[(size_t)(row + r) * N + col] = acc[mi][ni][r] + bv;
        }
    }
}

// ---------------------------------------------------------------------------
extern "C" void kernel_launch(void* const* d_in, const int* in_sizes, int n_in,
                              void* d_out, int out_size, void* d_ws, size_t ws_size,
                              hipStream_t stream)
{
    const int*   m     = (const int*)d_in[0];
    const float* emb   = (const float*)d_in[1];
    const float* W_ih  = (const float*)d_in[2];
    const float* W_hh  = (const float*)d_in[3];
    const float* b_ih  = (const float*)d_in[4];
    const float* b_hh  = (const float*)d_in[5];
    const float* W_out = (const float*)d_in[6];
    const float* b_out = (const float*)d_in[7];
    float* out = (float*)d_out;

    char* w = (char*)d_ws;
    size_t off = 0;
    auto alloc = [&](size_t bytes) {
        char* p = w + off;
        off = (off + bytes + 255) & ~(size_t)255;
        return p;
    };
    _Float16* emb16   = (_Float16*)alloc((size_t)VOCAB_ * EMB_ * 2);
    _Float16* Wc16    = (_Float16*)alloc((size_t)G4H_ * KCAT_ * 2);
    _Float16* Wout16  = (_Float16*)alloc((size_t)NIMG_ * HID_ * 2);
    float*    biasp   = (float*)   alloc((size_t)G4H_ * 4);
    _Float16* hA      = (_Float16*)alloc((size_t)B_ * HID_ * 2);
    _Float16* hB      = (_Float16*)alloc((size_t)B_ * HID_ * 2);
    int*      tokperm = (int*)     alloc((size_t)B_ * T_ * 4);
    unsigned* cnt     = (unsigned*)alloc(256);

    // 1) convert / permute / init (also zeroes barrier counter)
    {
        const long long total = (long long)VOCAB_ * EMB_ + (long long)G4H_ * KCAT_ +
                                (long long)NIMG_ * HID_ + G4H_ +
                                (long long)B_ * HID_ + (long long)B_ * T_ + 1;
        convert_kernel<<<(int)((total + 255) / 256), 256, 0, stream>>>(
            m, emb, W_ih, W_hh, b_ih, b_hh, W_out,
            emb16, Wc16, Wout16, biasp, hA, tokperm, cnt);
    }

    // 2) entire recurrence in one persistent kernel (512 blocks, 2/CU)
    lstm_persistent<<<dim3(B_ / 64, G4H_ / 64), 256, 0, stream>>>(
        emb16, tokperm, Wc16, biasp, hA, hB, cnt);

    // 3) out = h @ W_out^T + b_out   (T even -> final h in hA)
    gemm_out<<<dim3(B_ / 64, NIMG_ / 128), 256, 0, stream>>>(
        hA, Wout16, b_out, out, NIMG_, HID_);
}

// Round 4
// 1881.090 us; speedup vs baseline: 2.0462x; 2.0462x over previous
//
#include <hip/hip_runtime.h>
#include <cstdint>

#define B_    512
#define T_    64
#define VOCAB_ 10000
#define VPAD_ 10112     // vocab padded to 128
#define EMB_  512
#define HID_  1024
#define G4H_  4096      // 4*HID
#define KCAT_ 1536      // EMB + HID
#define NIMG_ 2048
#define NBLK_ 256       // persistent grid (4 bx, 64 by)

typedef _Float16 half8 __attribute__((ext_vector_type(8)));
typedef _Float16 half4 __attribute__((ext_vector_type(4)));
typedef float floatx4 __attribute__((ext_vector_type(4)));

// Async global->LDS, 16B per lane. LDS dest = wave-uniform base (HW adds
// lane*16). Per-lane SOURCE address is free (gather OK).
__device__ __forceinline__ void async_copy16(void* lds_uniform, const void* gsrc) {
    __builtin_amdgcn_global_load_lds(
        (__attribute__((address_space(1))) void*)(uintptr_t)gsrc,
        (__attribute__((address_space(3))) void*)(uint32_t)(uintptr_t)lds_uniform,
        16, 0, 0);
}

__device__ __forceinline__ float fsig(float x)  { return 1.0f / (1.0f + __expf(-x)); }
__device__ __forceinline__ float ftanh(float x) { return 1.0f - 2.0f / (__expf(2.0f * x) + 1.0f); }

// Gate-interleaved weight-row permutation:
//   n_perm = jblk*64 + gate*16 + jlo   <->   n_orig = gate*HID + (jblk*16 + jlo)

// ---------------------------------------------------------------------------
// One-time: emb->f16, Wc16 = permuted [W_ih|W_hh] (4096 x 1536), Wout16,
// biasp = permuted (b_ih+b_hh), hA = 0, tokperm[t*B+b] = m[b][t], cnt = 0.
// ---------------------------------------------------------------------------
__global__ __launch_bounds__(256) void convert_kernel(
    const int* __restrict__ m, const float* __restrict__ emb,
    const float* __restrict__ W_ih, const float* __restrict__ W_hh,
    const float* __restrict__ b_ih, const float* __restrict__ b_hh,
    const float* __restrict__ W_out,
    _Float16* __restrict__ emb16, _Float16* __restrict__ Wc16,
    _Float16* __restrict__ Wout16, float* __restrict__ biasp,
    _Float16* __restrict__ hA, int* __restrict__ tokperm,
    unsigned* __restrict__ cnt)
{
    const long long EMB_N = (long long)VOCAB_ * EMB_;
    const long long WC_N  = (long long)G4H_ * KCAT_;
    const long long WO_N  = (long long)NIMG_ * HID_;
    const long long BI_N  = G4H_;
    const long long ST_N  = (long long)B_ * HID_;
    const long long TK_N  = (long long)B_ * T_;

    long long i = (long long)blockIdx.x * 256 + threadIdx.x;
    if (i < EMB_N) { emb16[i] = (_Float16)emb[i]; return; }
    i -= EMB_N;
    if (i < WC_N) {
        int n_perm = (int)(i / KCAT_);
        int k      = (int)(i % KCAT_);
        int gate = (n_perm >> 4) & 3;
        int j    = (n_perm >> 6) * 16 + (n_perm & 15);
        int n_orig = gate * HID_ + j;
        float v = (k < EMB_) ? W_ih[(size_t)n_orig * EMB_ + k]
                             : W_hh[(size_t)n_orig * HID_ + (k - EMB_)];
        Wc16[i] = (_Float16)v;
        return;
    }
    i -= WC_N;
    if (i < WO_N) { Wout16[i] = (_Float16)W_out[i]; return; }
    i -= WO_N;
    if (i < BI_N) {
        int n_perm = (int)i;
        int gate = (n_perm >> 4) & 3;
        int j    = (n_perm >> 6) * 16 + (n_perm & 15);
        biasp[i] = b_ih[gate * HID_ + j] + b_hh[gate * HID_ + j];
        return;
    }
    i -= BI_N;
    if (i < ST_N) { hA[i] = (_Float16)0.0f; return; }
    i -= ST_N;
    if (i < TK_N) {
        int t = (int)(i / B_), b = (int)(i % B_);
        tokperm[i] = m[(size_t)b * T_ + t];
        return;
    }
    i -= TK_N;
    if (i == 0) *cnt = 0u;
}

// ---------------------------------------------------------------------------
// PE table GEMM: PEx[v][jblk*64 + jlo*4 + g] = emb[v] @ W_ih_perm^T + biasp
// (gate-packed: the 4 gates of (v,j) are contiguous -> persistent kernel's
// acc-init is one 8B load per row). 128x128 tile, K=512.
// ---------------------------------------------------------------------------
__global__ __launch_bounds__(256) void gemm_pe(
    const _Float16* __restrict__ emb16, const _Float16* __restrict__ Wc16,
    const float* __restrict__ biasp, _Float16* __restrict__ PEx)
{
    __shared__ __align__(16) _Float16 As[128 * 32];
    __shared__ __align__(16) _Float16 Bs[128 * 32];

    const int tid  = threadIdx.x;
    const int wid  = tid >> 6;
    const int lane = tid & 63;
    const int lcol = lane & 15;
    const int quad = lane >> 4;
    const int wm   = wid >> 1;
    const int wn   = wid & 1;

    const int r0 = blockIdx.x * 128;
    const int n0 = blockIdx.y * 128;

    floatx4 acc[4][4];
#pragma unroll
    for (int i = 0; i < 4; ++i)
#pragma unroll
        for (int j = 0; j < 4; ++j) acc[i][j] = (floatx4){0.f, 0.f, 0.f, 0.f};

    const int ar = tid >> 2;
    const int kq = tid & 3;

    for (int k0 = 0; k0 < EMB_; k0 += 32) {
        async_copy16((char*)As + (wid << 10),
                     emb16 + (size_t)(r0 + ar) * EMB_ + (k0 + kq * 8));
        async_copy16((char*)As + 4096 + (wid << 10),
                     emb16 + (size_t)(r0 + 64 + ar) * EMB_ + (k0 + kq * 8));
        async_copy16((char*)Bs + (wid << 10),
                     Wc16 + (size_t)(n0 + ar) * KCAT_ + (k0 + kq * 8));
        async_copy16((char*)Bs + 4096 + (wid << 10),
                     Wc16 + (size_t)(n0 + 64 + ar) * KCAT_ + (k0 + kq * 8));
        __syncthreads();

        half8 af[4], bf[4];
#pragma unroll
        for (int mi = 0; mi < 4; ++mi)
            af[mi] = *(const half8*)&As[(wm * 64 + mi * 16 + lcol) * 32 + quad * 8];
#pragma unroll
        for (int ni = 0; ni < 4; ++ni)
            bf[ni] = *(const half8*)&Bs[(wn * 64 + ni * 16 + lcol) * 32 + quad * 8];
#pragma unroll
        for (int mi = 0; mi < 4; ++mi)
#pragma unroll
            for (int ni = 0; ni < 4; ++ni)
                acc[mi][ni] = __builtin_amdgcn_mfma_f32_16x16x32_f16(
                    af[mi], bf[ni], acc[mi][ni], 0, 0, 0);
        __syncthreads();
    }

    // Epilogue: cols n0+wn*64+ni*16+lcol share jblk=(n0+wn*64)>>6, jlo=lcol,
    // g=ni -> thread's 4 gate values are contiguous: one half4 store per row.
    const int jblk = (n0 + wn * 64) >> 6;
    float bv[4];
#pragma unroll
    for (int ni = 0; ni < 4; ++ni) bv[ni] = biasp[n0 + wn * 64 + ni * 16 + lcol];
#pragma unroll
    for (int mi = 0; mi < 4; ++mi) {
#pragma unroll
        for (int r = 0; r < 4; ++r) {
            const int row = r0 + wm * 64 + mi * 16 + quad * 4 + r;
            half4 v;
#pragma unroll
            for (int ni = 0; ni < 4; ++ni)
                v[ni] = (_Float16)(acc[mi][ni][r] + bv[ni]);
            *(half4*)(PEx + (size_t)row * G4H_ + jblk * 64 + lcol * 4) = v;
        }
    }
}

// ---------------------------------------------------------------------------
// Persistent LSTM: all 64 steps in one launch. Grid (4,64)=256 blocks, 1/CU.
// Tile 128 rows x 64 perm-cols. W (64 x 1024 recurrent K) lives in LDS,
// XOR-swizzled, loaded ONCE. A = h_prev staged via ring-3 global_load_lds
// slabs with raw s_barrier + s_waitcnt vmcnt(4) (prefetch stays in flight).
// Wave = 32 rows x all 4 gates -> no cross-wave epilogue exchange.
// c-state in 8 VGPRs. PE acc-init prefetched before the device barrier.
// ---------------------------------------------------------------------------
__global__ __launch_bounds__(256, 1) void lstm_persistent(
    const _Float16* __restrict__ PEx, const int* __restrict__ tokperm,
    const _Float16* __restrict__ Wc16,
    _Float16* __restrict__ hA, _Float16* __restrict__ hB,
    unsigned* __restrict__ cnt)
{
    // 131072 (W swizzled) + 3*8192 (A ring) = 155648 B
    __shared__ __align__(16) char smem[131072 + 3 * 8192];
    char* Aring = smem + 131072;

    const int tid  = threadIdx.x;
    const int wid  = tid >> 6;
    const int lane = tid & 63;
    const int lcol = lane & 15;
    const int quad = lane >> 4;
    const int b0   = blockIdx.x * 128;
    const int by   = blockIdx.y;
    const int n0   = by * 64;

    // ---- W preload: 64 cols x 1024 k (recurrent part), 16B chunks swizzled
    // chunk' = chunk ^ (col&7): b128 reads hit minimal 8 bank-phases, no pad.
#pragma unroll 4
    for (int c = 0; c < 32; ++c) {
        const int q     = tid + c * 256;   // 0..8191
        const int col   = q >> 7;          // 0..63
        const int chunk = q & 127;         // 16B units along k
        half8 v = *(const half8*)(Wc16 + (size_t)(n0 + col) * KCAT_ + EMB_ + chunk * 8);
        *(half8*)(smem + col * 2048 + (chunk ^ (col & 7)) * 16) = v;
    }

    // Thread's output coords: rows wid*32+mi*16+quad*4+r (mi 0..1), col j=by*16+lcol
    float cst[2][4] = {{0.f, 0.f, 0.f, 0.f}, {0.f, 0.f, 0.f, 0.f}};
    half4 pe[2][4];

    // PE prefetch for t=0
#pragma unroll
    for (int mi = 0; mi < 2; ++mi)
#pragma unroll
        for (int r = 0; r < 4; ++r) {
            const int row = wid * 32 + mi * 16 + quad * 4 + r;
            const int tk = tokperm[b0 + row];
            pe[mi][r] = *(const half4*)(PEx + (size_t)tk * G4H_ + by * 64 + lcol * 4);
        }

    __syncthreads();  // W in LDS visible to all waves

    const int sr = lane >> 2;        // staging row within 64-group
    const int sk = (lane & 3) * 8;   // k halves within k32

    for (int t = 0; t < T_; ++t) {
        const _Float16* h_prev = (t & 1) ? hB : hA;
        _Float16*       h_next = (t & 1) ? hA : hB;

        auto issue_slab = [&](int s) {
            const _Float16* src0 = h_prev + (size_t)(b0 + wid * 16 + sr) * HID_ + s * 32 + sk;
            char* dst = Aring + (s % 3) * 8192 + wid * 1024;
            async_copy16(dst,        src0);
            async_copy16(dst + 4096, src0 + (size_t)64 * HID_);
        };

        issue_slab(0);
        issue_slab(1);

        // acc init from PE (compiler inserts the exact vmcnt for pe loads)
        floatx4 acc[2][4];
#pragma unroll
        for (int mi = 0; mi < 2; ++mi)
#pragma unroll
            for (int g = 0; g < 4; ++g)
#pragma unroll
                for (int r = 0; r < 4; ++r)
                    acc[mi][g][r] = (float)pe[mi][r][g];

        // ---- K loop: 32 k32 iters, ring-3, prefetch distance 2 ----
#pragma unroll
        for (int s = 0; s < 32; ++s) {
            if (s + 2 < 32) issue_slab(s + 2);
            if (s < 30)       asm volatile("s_waitcnt vmcnt(4)" ::: "memory");
            else if (s == 30) asm volatile("s_waitcnt vmcnt(2)" ::: "memory");
            else              asm volatile("s_waitcnt vmcnt(0)" ::: "memory");
            __builtin_amdgcn_s_barrier();  // all waves' slab-s DMA complete

            const _Float16* As = (const _Float16*)(Aring + (s % 3) * 8192);
            half8 af0 = *(const half8*)&As[(wid * 32 + lcol) * 32 + quad * 8];
            half8 af1 = *(const half8*)&As[(wid * 32 + 16 + lcol) * 32 + quad * 8];
            const int chb = (((s * 4 + quad) ^ (lcol & 7)) << 4);  // swizzled byte off
#pragma unroll
            for (int g = 0; g < 4; ++g) {
                half8 bw = *(const half8*)(smem + (g * 16 + lcol) * 2048 + chb);
                acc[0][g] = __builtin_amdgcn_mfma_f32_16x16x32_f16(af0, bw, acc[0][g], 0, 0, 0);
                acc[1][g] = __builtin_amdgcn_mfma_f32_16x16x32_f16(af1, bw, acc[1][g], 0, 0, 0);
            }
        }

        // ---- fused LSTM cell (no cross-wave exchange needed) ----
#pragma unroll
        for (int mi = 0; mi < 2; ++mi)
#pragma unroll
            for (int r = 0; r < 4; ++r) {
                const int row = wid * 32 + mi * 16 + quad * 4 + r;
                const float iv = fsig(acc[mi][0][r]);
                const float fv = fsig(acc[mi][1][r]);
                const float gv = ftanh(acc[mi][2][r]);
                const float ov = fsig(acc[mi][3][r]);
                cst[mi][r] = fv * cst[mi][r] + iv * gv;
                h_next[(size_t)(b0 + row) * HID_ + by * 16 + lcol] =
                    (_Float16)(ov * ftanh(cst[mi][r]));
            }

        // ---- device-scope barrier between steps ----
        __syncthreads();  // drains h stores (vmcnt 0) before the fence
        if (tid == 0) {
            __threadfence();
            __hip_atomic_fetch_add(cnt, 1u, __ATOMIC_RELEASE, __HIP_MEMORY_SCOPE_AGENT);
            const unsigned target = (unsigned)(t + 1) * NBLK_;
            while (__hip_atomic_load(cnt, __ATOMIC_ACQUIRE, __HIP_MEMORY_SCOPE_AGENT) < target)
                __builtin_amdgcn_s_sleep(4);
        }
        // PE prefetch for t+1 (constant data: safe pre-barrier, overlaps spin)
        if (t + 1 < T_) {
#pragma unroll
            for (int mi = 0; mi < 2; ++mi)
#pragma unroll
                for (int r = 0; r < 4; ++r) {
                    const int row = wid * 32 + mi * 16 + quad * 4 + r;
                    const int tk = tokperm[(t + 1) * B_ + b0 + row];
                    pe[mi][r] = *(const half4*)(PEx + (size_t)tk * G4H_ + by * 64 + lcol * 4);
                }
        }
        __builtin_amdgcn_s_barrier();  // release all waves after leader's acquire
    }
}

// ---------------------------------------------------------------------------
// Final projection GEMM (unpermuted): Out = h @ Wout16^T + b_out
// ---------------------------------------------------------------------------
__global__ __launch_bounds__(256) void gemm_out(
    const _Float16* __restrict__ A, const _Float16* __restrict__ Bw,
    const float* __restrict__ bias, float* __restrict__ Out, int N, int K)
{
    __shared__ __align__(16) _Float16 As[64 * 32];
    __shared__ __align__(16) _Float16 Bs[128 * 32];

    const int tid  = threadIdx.x;
    const int wid  = tid >> 6;
    const int lane = tid & 63;
    const int lcol = lane & 15;
    const int quad = lane >> 4;
    const int wm   = wid >> 1;
    const int wn   = wid & 1;

    const int b0 = blockIdx.x * 64;
    const int n0 = blockIdx.y * 128;

    floatx4 acc[2][4];
#pragma unroll
    for (int i = 0; i < 2; ++i)
#pragma unroll
        for (int j = 0; j < 4; ++j) acc[i][j] = (floatx4){0.f, 0.f, 0.f, 0.f};

    const int ar = tid >> 2;
    const int kq = tid & 3;

    for (int k0 = 0; k0 < K; k0 += 32) {
        async_copy16((char*)As + (wid << 10), A + (size_t)(b0 + ar) * K + (k0 + kq * 8));
        async_copy16((char*)Bs + (wid << 10), Bw + (size_t)(n0 + ar) * K + (k0 + kq * 8));
        async_copy16((char*)Bs + 4096 + (wid << 10),
                     Bw + (size_t)(n0 + 64 + ar) * K + (k0 + kq * 8));
        __syncthreads();

        half8 af[2], bfr[4];
#pragma unroll
        for (int mi = 0; mi < 2; ++mi)
            af[mi] = *(const half8*)&As[(wm * 32 + mi * 16 + lcol) * 32 + quad * 8];
#pragma unroll
        for (int ni = 0; ni < 4; ++ni)
            bfr[ni] = *(const half8*)&Bs[(wn * 64 + ni * 16 + lcol) * 32 + quad * 8];
#pragma unroll
        for (int mi = 0; mi < 2; ++mi)
#pragma unroll
            for (int ni = 0; ni < 4; ++ni)
                acc[mi][ni] = __builtin_amdgcn_mfma_f32_16x16x32_f16(
                    af[mi], bfr[ni], acc[mi][ni], 0, 0, 0);
        __syncthreads();
    }

#pragma unroll
    for (int mi = 0; mi < 2; ++mi) {
#pragma unroll
        for (int ni = 0; ni < 4; ++ni) {
            const int row = b0 + wm * 32 + mi * 16 + quad * 4;
            const int col = n0 + wn * 64 + ni * 16 + lcol;
            const float bv = bias[col];
#pragma unroll
            for (int r = 0; r < 4; ++r)
                Out[(size_t)(row + r) * N + col] = acc[mi][ni][r] + bv;
        }
    }
}

// ---------------------------------------------------------------------------
extern "C" void kernel_launch(void* const* d_in, const int* in_sizes, int n_in,
                              void* d_out, int out_size, void* d_ws, size_t ws_size,
                              hipStream_t stream)
{
    const int*   m     = (const int*)d_in[0];
    const float* emb   = (const float*)d_in[1];
    const float* W_ih  = (const float*)d_in[2];
    const float* W_hh  = (const float*)d_in[3];
    const float* b_ih  = (const float*)d_in[4];
    const float* b_hh  = (const float*)d_in[5];
    const float* W_out = (const float*)d_in[6];
    const float* b_out = (const float*)d_in[7];
    float* out = (float*)d_out;

    char* w = (char*)d_ws;
    size_t off = 0;
    auto alloc = [&](size_t bytes) {
        char* p = w + off;
        off = (off + bytes + 255) & ~(size_t)255;
        return p;
    };
    _Float16* emb16   = (_Float16*)alloc((size_t)VPAD_ * EMB_ * 2);
    _Float16* Wc16    = (_Float16*)alloc((size_t)G4H_ * KCAT_ * 2);
    _Float16* Wout16  = (_Float16*)alloc((size_t)NIMG_ * HID_ * 2);
    float*    biasp   = (float*)   alloc((size_t)G4H_ * 4);
    _Float16* hA      = (_Float16*)alloc((size_t)B_ * HID_ * 2);
    _Float16* hB      = (_Float16*)alloc((size_t)B_ * HID_ * 2);
    int*      tokperm = (int*)     alloc((size_t)B_ * T_ * 4);
    unsigned* cnt     = (unsigned*)alloc(256);
    _Float16* PEx     = (_Float16*)alloc((size_t)VPAD_ * G4H_ * 2);  // 83 MB

    // 1) convert / permute / init
    {
        const long long total = (long long)VOCAB_ * EMB_ + (long long)G4H_ * KCAT_ +
                                (long long)NIMG_ * HID_ + G4H_ +
                                (long long)B_ * HID_ + (long long)B_ * T_ + 1;
        convert_kernel<<<(int)((total + 255) / 256), 256, 0, stream>>>(
            m, emb, W_ih, W_hh, b_ih, b_hh, W_out,
            emb16, Wc16, Wout16, biasp, hA, tokperm, cnt);
    }

    // 2) PE table: emb @ W_ih^T + bias for all vocab rows (gate-packed)
    gemm_pe<<<dim3(VPAD_ / 128, G4H_ / 128), 256, 0, stream>>>(
        emb16, Wc16, biasp, PEx);

    // 3) entire recurrence in one persistent kernel (256 blocks, 1/CU)
    lstm_persistent<<<dim3(B_ / 128, G4H_ / 64), 256, 0, stream>>>(
        PEx, tokperm, Wc16, hA, hB, cnt);

    // 4) out = h @ W_out^T + b_out   (T even -> final h in hA)
    gemm_out<<<dim3(B_ / 64, NIMG_ / 128), 256, 0, stream>>>(
        hA, Wout16, b_out, out, NIMG_, HID_);
}

// Round 5
// 1756.592 us; speedup vs baseline: 2.1912x; 1.0709x over previous
//
#include <hip/hip_runtime.h>
#include <cstdint>

#define B_    512
#define T_    64
#define VOCAB_ 10000
#define VPAD_ 10112     // vocab padded to 128
#define EMB_  512
#define HID_  1024
#define G4H_  4096      // 4*HID
#define KCAT_ 1536      // EMB + HID
#define NIMG_ 2048
#define NBLK_ 256       // persistent grid (4 bx, 64 by)

typedef _Float16 half8 __attribute__((ext_vector_type(8)));
typedef _Float16 half4 __attribute__((ext_vector_type(4)));
typedef float floatx4 __attribute__((ext_vector_type(4)));

// Async global->LDS, 16B per lane. LDS dest = wave-uniform base (HW adds
// lane*16). Per-lane SOURCE address is free (gather OK).
__device__ __forceinline__ void async_copy16(void* lds_uniform, const void* gsrc) {
    __builtin_amdgcn_global_load_lds(
        (__attribute__((address_space(1))) void*)(uintptr_t)gsrc,
        (__attribute__((address_space(3))) void*)(uint32_t)(uintptr_t)lds_uniform,
        16, 0, 0);
}

__device__ __forceinline__ float fsig(float x)  { return 1.0f / (1.0f + __expf(-x)); }
__device__ __forceinline__ float ftanh(float x) { return 1.0f - 2.0f / (__expf(2.0f * x) + 1.0f); }

// Gate-interleaved weight-row permutation:
//   n_perm = jblk*64 + gate*16 + jlo   <->   n_orig = gate*HID + (jblk*16 + jlo)

// ---------------------------------------------------------------------------
// One-time: emb->f16, Wc16 = permuted [W_ih|W_hh] (4096 x 1536), Wout16,
// biasp = permuted (b_ih+b_hh), hA = 0, tokperm[t*B+b] = m[b][t], cnt = 0.
// ---------------------------------------------------------------------------
__global__ __launch_bounds__(256) void convert_kernel(
    const int* __restrict__ m, const float* __restrict__ emb,
    const float* __restrict__ W_ih, const float* __restrict__ W_hh,
    const float* __restrict__ b_ih, const float* __restrict__ b_hh,
    const float* __restrict__ W_out,
    _Float16* __restrict__ emb16, _Float16* __restrict__ Wc16,
    _Float16* __restrict__ Wout16, float* __restrict__ biasp,
    _Float16* __restrict__ hA, int* __restrict__ tokperm,
    unsigned* __restrict__ cnt)
{
    const long long EMB_N = (long long)VOCAB_ * EMB_;
    const long long WC_N  = (long long)G4H_ * KCAT_;
    const long long WO_N  = (long long)NIMG_ * HID_;
    const long long BI_N  = G4H_;
    const long long ST_N  = (long long)B_ * HID_;
    const long long TK_N  = (long long)B_ * T_;

    long long i = (long long)blockIdx.x * 256 + threadIdx.x;
    if (i < EMB_N) { emb16[i] = (_Float16)emb[i]; return; }
    i -= EMB_N;
    if (i < WC_N) {
        int n_perm = (int)(i / KCAT_);
        int k      = (int)(i % KCAT_);
        int gate = (n_perm >> 4) & 3;
        int j    = (n_perm >> 6) * 16 + (n_perm & 15);
        int n_orig = gate * HID_ + j;
        float v = (k < EMB_) ? W_ih[(size_t)n_orig * EMB_ + k]
                             : W_hh[(size_t)n_orig * HID_ + (k - EMB_)];
        Wc16[i] = (_Float16)v;
        return;
    }
    i -= WC_N;
    if (i < WO_N) { Wout16[i] = (_Float16)W_out[i]; return; }
    i -= WO_N;
    if (i < BI_N) {
        int n_perm = (int)i;
        int gate = (n_perm >> 4) & 3;
        int j    = (n_perm >> 6) * 16 + (n_perm & 15);
        biasp[i] = b_ih[gate * HID_ + j] + b_hh[gate * HID_ + j];
        return;
    }
    i -= BI_N;
    if (i < ST_N) { hA[i] = (_Float16)0.0f; return; }
    i -= ST_N;
    if (i < TK_N) {
        int t = (int)(i / B_), b = (int)(i % B_);
        tokperm[i] = m[(size_t)b * T_ + t];
        return;
    }
    i -= TK_N;
    if (i == 0) *cnt = 0u;
}

// ---------------------------------------------------------------------------
// PE table GEMM: PEx[v][jblk*64 + jlo*4 + g] = emb[v] @ W_ih_perm^T + biasp
// (gate-packed: the 4 gates of (v,j) are contiguous -> persistent kernel's
// acc-init is one 8B load per row). 128x128 tile, K=512.
// ---------------------------------------------------------------------------
__global__ __launch_bounds__(256) void gemm_pe(
    const _Float16* __restrict__ emb16, const _Float16* __restrict__ Wc16,
    const float* __restrict__ biasp, _Float16* __restrict__ PEx)
{
    __shared__ __align__(16) _Float16 As[128 * 32];
    __shared__ __align__(16) _Float16 Bs[128 * 32];

    const int tid  = threadIdx.x;
    const int wid  = tid >> 6;
    const int lane = tid & 63;
    const int lcol = lane & 15;
    const int quad = lane >> 4;
    const int wm   = wid >> 1;
    const int wn   = wid & 1;

    const int r0 = blockIdx.x * 128;
    const int n0 = blockIdx.y * 128;

    floatx4 acc[4][4];
#pragma unroll
    for (int i = 0; i < 4; ++i)
#pragma unroll
        for (int j = 0; j < 4; ++j) acc[i][j] = (floatx4){0.f, 0.f, 0.f, 0.f};

    const int ar = tid >> 2;
    const int kq = tid & 3;

    for (int k0 = 0; k0 < EMB_; k0 += 32) {
        async_copy16((char*)As + (wid << 10),
                     emb16 + (size_t)(r0 + ar) * EMB_ + (k0 + kq * 8));
        async_copy16((char*)As + 4096 + (wid << 10),
                     emb16 + (size_t)(r0 + 64 + ar) * EMB_ + (k0 + kq * 8));
        async_copy16((char*)Bs + (wid << 10),
                     Wc16 + (size_t)(n0 + ar) * KCAT_ + (k0 + kq * 8));
        async_copy16((char*)Bs + 4096 + (wid << 10),
                     Wc16 + (size_t)(n0 + 64 + ar) * KCAT_ + (k0 + kq * 8));
        __syncthreads();

        half8 af[4], bf[4];
#pragma unroll
        for (int mi = 0; mi < 4; ++mi)
            af[mi] = *(const half8*)&As[(wm * 64 + mi * 16 + lcol) * 32 + quad * 8];
#pragma unroll
        for (int ni = 0; ni < 4; ++ni)
            bf[ni] = *(const half8*)&Bs[(wn * 64 + ni * 16 + lcol) * 32 + quad * 8];
#pragma unroll
        for (int mi = 0; mi < 4; ++mi)
#pragma unroll
            for (int ni = 0; ni < 4; ++ni)
                acc[mi][ni] = __builtin_amdgcn_mfma_f32_16x16x32_f16(
                    af[mi], bf[ni], acc[mi][ni], 0, 0, 0);
        __syncthreads();
    }

    // Epilogue: cols n0+wn*64+ni*16+lcol share jblk=(n0+wn*64)>>6, jlo=lcol,
    // g=ni -> thread's 4 gate values are contiguous: one half4 store per row.
    const int jblk = (n0 + wn * 64) >> 6;
    float bv[4];
#pragma unroll
    for (int ni = 0; ni < 4; ++ni) bv[ni] = biasp[n0 + wn * 64 + ni * 16 + lcol];
#pragma unroll
    for (int mi = 0; mi < 4; ++mi) {
#pragma unroll
        for (int r = 0; r < 4; ++r) {
            const int row = r0 + wm * 64 + mi * 16 + quad * 4 + r;
            half4 v;
#pragma unroll
            for (int ni = 0; ni < 4; ++ni)
                v[ni] = (_Float16)(acc[mi][ni][r] + bv[ni]);
            *(half4*)(PEx + (size_t)row * G4H_ + jblk * 64 + lcol * 4) = v;
        }
    }
}

// ---------------------------------------------------------------------------
// Persistent LSTM: all 64 steps in one launch. Grid (4,64)=256 blocks, 1/CU.
// Tile 128 rows x 64 perm-cols. W (64 x 1024 recurrent K) in LDS, XOR-
// swizzled, loaded ONCE. BARRIER-FREE K-loop: each wave stages its OWN 32
// A-rows into a private per-wave LDS ring (3 x 2KB), self-paced with
// per-wave s_waitcnt vmcnt(4) -- no s_barrier until the step epilogue.
// Wave = 32 rows x all 4 gates -> no cross-wave epilogue exchange.
// c-state in 8 VGPRs. PE acc-init prefetched during the barrier spin.
// ---------------------------------------------------------------------------
__global__ __launch_bounds__(256, 1) void lstm_persistent(
    const _Float16* __restrict__ PEx, const int* __restrict__ tokperm,
    const _Float16* __restrict__ Wc16,
    _Float16* __restrict__ hA, _Float16* __restrict__ hB,
    unsigned* __restrict__ cnt)
{
    // 131072 (W swizzled) + 3 slabs x 8KB (4 waves x 2KB each) = 155648 B
    __shared__ __align__(16) char smem[131072 + 3 * 8192];
    char* Aring = smem + 131072;

    const int tid  = threadIdx.x;
    const int wid  = tid >> 6;
    const int lane = tid & 63;
    const int lcol = lane & 15;
    const int quad = lane >> 4;
    const int b0   = blockIdx.x * 128;
    const int by   = blockIdx.y;
    const int n0   = by * 64;

    // ---- W preload: 64 cols x 1024 k (recurrent part), 16B chunks swizzled
    // chunk' = chunk ^ (col&7): b128 reads spread bank phases, no padding.
#pragma unroll 4
    for (int c = 0; c < 32; ++c) {
        const int q     = tid + c * 256;   // 0..8191
        const int col   = q >> 7;          // 0..63
        const int chunk = q & 127;         // 16B units along k
        half8 v = *(const half8*)(Wc16 + (size_t)(n0 + col) * KCAT_ + EMB_ + chunk * 8);
        *(half8*)(smem + col * 2048 + (chunk ^ (col & 7)) * 16) = v;
    }

    // Thread's outputs: rows wid*32+mi*16+quad*4+r (mi 0..1), col j=by*16+lcol
    float cst[2][4] = {{0.f, 0.f, 0.f, 0.f}, {0.f, 0.f, 0.f, 0.f}};
    half4 pe[2][4];

    // PE prefetch for t=0
#pragma unroll
    for (int mi = 0; mi < 2; ++mi)
#pragma unroll
        for (int r = 0; r < 4; ++r) {
            const int row = wid * 32 + mi * 16 + quad * 4 + r;
            const int tk = tokperm[b0 + row];
            pe[mi][r] = *(const half4*)(PEx + (size_t)tk * G4H_ + by * 64 + lcol * 4);
        }

    __syncthreads();  // W in LDS visible to all waves

    // Per-wave private A staging: this wave's rows b0+wid*32 .. +31.
    // Slab layout: 32 rows x 64B (k32), exactly lane*16-linear.
    const int srow = lane >> 2;        // 0..15 (row within 16-row group)
    const int sk   = (lane & 3) * 8;   // k halves within k32

    for (int t = 0; t < T_; ++t) {
        const _Float16* h_prev = (t & 1) ? hB : hA;
        _Float16*       h_next = (t & 1) ? hA : hB;

        const _Float16* hbase = h_prev + (size_t)(b0 + wid * 32 + srow) * HID_ + sk;

        auto issue_slab = [&](int s) {
            char* dst = Aring + (s % 3) * 8192 + wid * 2048;
            async_copy16(dst,        hbase + s * 32);                     // rows +0..15
            async_copy16(dst + 1024, hbase + s * 32 + (size_t)16 * HID_); // rows +16..31
        };

        issue_slab(0);
        issue_slab(1);

        // acc init from PE (compiler inserts the precise vmcnt for pe regs)
        floatx4 acc[2][4];
#pragma unroll
        for (int mi = 0; mi < 2; ++mi)
#pragma unroll
            for (int g = 0; g < 4; ++g)
#pragma unroll
                for (int r = 0; r < 4; ++r)
                    acc[mi][g][r] = (float)pe[mi][r][g];

        // ---- BARRIER-FREE K loop: 32 k32 iters, ring-3, depth-2 prefetch ----
#pragma unroll
        for (int s = 0; s < 32; ++s) {
            if (s + 2 < 32) issue_slab(s + 2);
            // per-wave wait: slab s complete (slabs s+1,s+2 still in flight)
            if (s < 30)       asm volatile("s_waitcnt vmcnt(4)" ::: "memory");
            else if (s == 30) asm volatile("s_waitcnt vmcnt(2)" ::: "memory");
            else              asm volatile("s_waitcnt vmcnt(0)" ::: "memory");

            const char* slab = Aring + (s % 3) * 8192 + wid * 2048;
            half8 af0 = *(const half8*)(slab + (lcol)      * 64 + quad * 16);
            half8 af1 = *(const half8*)(slab + (16 + lcol) * 64 + quad * 16);
            const int chb = (((s * 4 + quad) ^ (lcol & 7)) << 4);  // swizzled
#pragma unroll
            for (int g = 0; g < 4; ++g) {
                half8 bw = *(const half8*)(smem + (g * 16 + lcol) * 2048 + chb);
                acc[0][g] = __builtin_amdgcn_mfma_f32_16x16x32_f16(af0, bw, acc[0][g], 0, 0, 0);
                acc[1][g] = __builtin_amdgcn_mfma_f32_16x16x32_f16(af1, bw, acc[1][g], 0, 0, 0);
            }
        }

        // ---- fused LSTM cell (wave-private; no exchange) ----
#pragma unroll
        for (int mi = 0; mi < 2; ++mi)
#pragma unroll
            for (int r = 0; r < 4; ++r) {
                const int row = wid * 32 + mi * 16 + quad * 4 + r;
                const float iv = fsig(acc[mi][0][r]);
                const float fv = fsig(acc[mi][1][r]);
                const float gv = ftanh(acc[mi][2][r]);
                const float ov = fsig(acc[mi][3][r]);
                cst[mi][r] = fv * cst[mi][r] + iv * gv;
                h_next[(size_t)(b0 + row) * HID_ + by * 16 + lcol] =
                    (_Float16)(ov * ftanh(cst[mi][r]));
            }

        // ---- device-scope barrier between steps (proven protocol) ----
        __syncthreads();  // drains vmcnt: h stores complete
        if (tid == 0) {
            __threadfence();
            __hip_atomic_fetch_add(cnt, 1u, __ATOMIC_RELEASE, __HIP_MEMORY_SCOPE_AGENT);
            const unsigned target = (unsigned)(t + 1) * NBLK_;
            while (__hip_atomic_load(cnt, __ATOMIC_ACQUIRE, __HIP_MEMORY_SCOPE_AGENT) < target)
                __builtin_amdgcn_s_sleep(2);
        }
        // PE prefetch for t+1 (constant data: safe pre-barrier, overlaps spin)
        if (t + 1 < T_) {
#pragma unroll
            for (int mi = 0; mi < 2; ++mi)
#pragma unroll
                for (int r = 0; r < 4; ++r) {
                    const int row = wid * 32 + mi * 16 + quad * 4 + r;
                    const int tk = tokperm[(t + 1) * B_ + b0 + row];
                    pe[mi][r] = *(const half4*)(PEx + (size_t)tk * G4H_ + by * 64 + lcol * 4);
                }
        }
        __builtin_amdgcn_s_barrier();  // release all waves after leader's acquire
    }
}

// ---------------------------------------------------------------------------
// Final projection GEMM (unpermuted): Out = h @ Wout16^T + b_out
// ---------------------------------------------------------------------------
__global__ __launch_bounds__(256) void gemm_out(
    const _Float16* __restrict__ A, const _Float16* __restrict__ Bw,
    const float* __restrict__ bias, float* __restrict__ Out, int N, int K)
{
    __shared__ __align__(16) _Float16 As[64 * 32];
    __shared__ __align__(16) _Float16 Bs[128 * 32];

    const int tid  = threadIdx.x;
    const int wid  = tid >> 6;
    const int lane = tid & 63;
    const int lcol = lane & 15;
    const int quad = lane >> 4;
    const int wm   = wid >> 1;
    const int wn   = wid & 1;

    const int b0 = blockIdx.x * 64;
    const int n0 = blockIdx.y * 128;

    floatx4 acc[2][4];
#pragma unroll
    for (int i = 0; i < 2; ++i)
#pragma unroll
        for (int j = 0; j < 4; ++j) acc[i][j] = (floatx4){0.f, 0.f, 0.f, 0.f};

    const int ar = tid >> 2;
    const int kq = tid & 3;

    for (int k0 = 0; k0 < K; k0 += 32) {
        async_copy16((char*)As + (wid << 10), A + (size_t)(b0 + ar) * K + (k0 + kq * 8));
        async_copy16((char*)Bs + (wid << 10), Bw + (size_t)(n0 + ar) * K + (k0 + kq * 8));
        async_copy16((char*)Bs + 4096 + (wid << 10),
                     Bw + (size_t)(n0 + 64 + ar) * K + (k0 + kq * 8));
        __syncthreads();

        half8 af[2], bfr[4];
#pragma unroll
        for (int mi = 0; mi < 2; ++mi)
            af[mi] = *(const half8*)&As[(wm * 32 + mi * 16 + lcol) * 32 + quad * 8];
#pragma unroll
        for (int ni = 0; ni < 4; ++ni)
            bfr[ni] = *(const half8*)&Bs[(wn * 64 + ni * 16 + lcol) * 32 + quad * 8];
#pragma unroll
        for (int mi = 0; mi < 2; ++mi)
#pragma unroll
            for (int ni = 0; ni < 4; ++ni)
                acc[mi][ni] = __builtin_amdgcn_mfma_f32_16x16x32_f16(
                    af[mi], bfr[ni], acc[mi][ni], 0, 0, 0);
        __syncthreads();
    }

#pragma unroll
    for (int mi = 0; mi < 2; ++mi) {
#pragma unroll
        for (int ni = 0; ni < 4; ++ni) {
            const int row = b0 + wm * 32 + mi * 16 + quad * 4;
            const int col = n0 + wn * 64 + ni * 16 + lcol;
            const float bv = bias[col];
#pragma unroll
            for (int r = 0; r < 4; ++r)
                Out[(size_t)(row + r) * N + col] = acc[mi][ni][r] + bv;
        }
    }
}

// ---------------------------------------------------------------------------
extern "C" void kernel_launch(void* const* d_in, const int* in_sizes, int n_in,
                              void* d_out, int out_size, void* d_ws, size_t ws_size,
                              hipStream_t stream)
{
    const int*   m     = (const int*)d_in[0];
    const float* emb   = (const float*)d_in[1];
    const float* W_ih  = (const float*)d_in[2];
    const float* W_hh  = (const float*)d_in[3];
    const float* b_ih  = (const float*)d_in[4];
    const float* b_hh  = (const float*)d_in[5];
    const float* W_out = (const float*)d_in[6];
    const float* b_out = (const float*)d_in[7];
    float* out = (float*)d_out;

    char* w = (char*)d_ws;
    size_t off = 0;
    auto alloc = [&](size_t bytes) {
        char* p = w + off;
        off = (off + bytes + 255) & ~(size_t)255;
        return p;
    };
    _Float16* emb16   = (_Float16*)alloc((size_t)VPAD_ * EMB_ * 2);
    _Float16* Wc16    = (_Float16*)alloc((size_t)G4H_ * KCAT_ * 2);
    _Float16* Wout16  = (_Float16*)alloc((size_t)NIMG_ * HID_ * 2);
    float*    biasp   = (float*)   alloc((size_t)G4H_ * 4);
    _Float16* hA      = (_Float16*)alloc((size_t)B_ * HID_ * 2);
    _Float16* hB      = (_Float16*)alloc((size_t)B_ * HID_ * 2);
    int*      tokperm = (int*)     alloc((size_t)B_ * T_ * 4);
    unsigned* cnt     = (unsigned*)alloc(256);
    _Float16* PEx     = (_Float16*)alloc((size_t)VPAD_ * G4H_ * 2);  // 83 MB

    // 1) convert / permute / init
    {
        const long long total = (long long)VOCAB_ * EMB_ + (long long)G4H_ * KCAT_ +
                                (long long)NIMG_ * HID_ + G4H_ +
                                (long long)B_ * HID_ + (long long)B_ * T_ + 1;
        convert_kernel<<<(int)((total + 255) / 256), 256, 0, stream>>>(
            m, emb, W_ih, W_hh, b_ih, b_hh, W_out,
            emb16, Wc16, Wout16, biasp, hA, tokperm, cnt);
    }

    // 2) PE table: emb @ W_ih^T + bias for all vocab rows (gate-packed)
    gemm_pe<<<dim3(VPAD_ / 128, G4H_ / 128), 256, 0, stream>>>(
        emb16, Wc16, biasp, PEx);

    // 3) entire recurrence in one persistent kernel (256 blocks, 1/CU)
    lstm_persistent<<<dim3(B_ / 128, G4H_ / 64), 256, 0, stream>>>(
        PEx, tokperm, Wc16, hA, hB, cnt);

    // 4) out = h @ W_out^T + b_out   (T even -> final h in hA)
    gemm_out<<<dim3(B_ / 64, NIMG_ / 128), 256, 0, stream>>>(
        hA, Wout16, b_out, out, NIMG_, HID_);
}